// Round 6
// baseline (281.347 us; speedup 1.0000x reference)
//
#include <hip/hip_runtime.h>

typedef float f32x4 __attribute__((ext_vector_type(4)));
typedef float f32x16 __attribute__((ext_vector_type(16)));
typedef __bf16 bf16x8 __attribute__((ext_vector_type(8)));
typedef unsigned short u16x8 __attribute__((ext_vector_type(8)));

#define SCQ 0.1803368801111183f  // 0.125 * log2(e): softmax in exp2 domain

__device__ inline unsigned short f2bf(float f) {
  unsigned int u = __builtin_bit_cast(unsigned int, f);
  u += 0x7FFFu + ((u >> 16) & 1u);
  return (unsigned short)(u >> 16);
}
// round-half-up bf16 for nonneg values (2 VALU)
__device__ inline unsigned short f2bf_fast(float f) {
  unsigned int u = __builtin_bit_cast(unsigned int, f);
  return (unsigned short)((u + 0x8000u) >> 16);
}

__device__ inline float fexp2(float x) {
#if __has_builtin(__builtin_amdgcn_exp2f)
  return __builtin_amdgcn_exp2f(x);
#else
  return exp2f(x);
#endif
}

// DPP rotate within 16-lane row (VALU pipe)
template <int N>
__device__ inline float rowror(float v) {
  return __builtin_bit_cast(float, __builtin_amdgcn_update_dpp(
      0, __builtin_bit_cast(int, v), 0x120 | N, 0xF, 0xF, true));
}
__device__ inline float rowsum16(float v) {
  v += rowror<8>(v); v += rowror<4>(v);
  v += rowror<2>(v); v += rowror<1>(v);
  return v;
}

__device__ inline void gload_lds16(const unsigned short* g, unsigned short* l) {
  __builtin_amdgcn_global_load_lds(
      (const __attribute__((address_space(1))) unsigned int*)g,
      (__attribute__((address_space(3))) unsigned int*)l, 16, 0, 0);
}

// ---------------- fp32 -> bf16 conversion ----------------
__global__ void cvt_x(const float* __restrict__ in, unsigned short* __restrict__ out) {
  int i = (blockIdx.x * 256 + threadIdx.x) * 4;
  float4 f = *(const float4*)(in + i);
  ushort4 o;
  o.x = f2bf(f.x); o.y = f2bf(f.y); o.z = f2bf(f.z); o.w = f2bf(f.w);
  *(ushort4*)(out + i) = o;
}

__global__ void cvt_w(const float* __restrict__ a, const float* __restrict__ b,
                      const float* __restrict__ c, const float* __restrict__ d,
                      unsigned short* __restrict__ oa, unsigned short* __restrict__ ob,
                      unsigned short* __restrict__ oc, unsigned short* __restrict__ od) {
  const float* src[4] = {a, b, c, d};
  unsigned short* dst[4] = {oa, ob, oc, od};
  int m = blockIdx.y;
  int i = (blockIdx.x * 256 + threadIdx.x) * 4;
  float4 f = *(const float4*)(src[m] + i);
  ushort4 o;
  o.x = f2bf(f.x); o.y = f2bf(f.y); o.z = f2bf(f.z); o.w = f2bf(f.w);
  *(ushort4*)(dst[m] + i) = o;
}

// ---------------- GEMM: out[m][n] = sum_k A[m][k]*Bt[n][k] + bias[n] ----------------
// 128x128 tile, BK=64, global_load_lds width16, XOR-swizzled chunks,
// 32x32x16 MFMA (2x2 per wave, 64x64 wave tile).
// MODE 0: fused QKV (N=3072): which=col>>10 selects bias b{0,1,2}, Q pre-scaled
//         by SCQ, bf16 scatter into out + which*8M, [B,H,T,D] layout.
// MODE 1: fp32 row-major MxN with bias b0.
template <int MODE>
__global__ __launch_bounds__(256) void gemm128(const unsigned short* __restrict__ A,
                                               const unsigned short* __restrict__ Bt,
                                               const float* __restrict__ b0,
                                               const float* __restrict__ b1,
                                               const float* __restrict__ b2,
                                               void* __restrict__ out,
                                               int M, int N, int K) {
  __shared__ __align__(16) unsigned short As[128 * 64];
  __shared__ __align__(16) unsigned short Bs[128 * 64];
  const int tid = threadIdx.x;
  const int lane = tid & 63, w = tid >> 6;
  const int l31 = lane & 31, half = lane >> 5;
  const int wm = w & 1, wn = w >> 1;
  const int m0 = blockIdx.x * 128, n0 = blockIdx.y * 128;

  f32x16 acc[2][2] = {};

  for (int kb = 0; kb < K; kb += 64) {
#pragma unroll
    for (int j = 0; j < 4; j++) {
      int ch = j * 256 + w * 64 + lane;
      int row = ch >> 3, pc = ch & 7;
      int c = pc ^ (row & 7);
      gload_lds16(A + (size_t)(m0 + row) * K + kb + c * 8, As + (size_t)(j * 256 + w * 64) * 8);
      gload_lds16(Bt + (size_t)(n0 + row) * K + kb + c * 8, Bs + (size_t)(j * 256 + w * 64) * 8);
    }
    __syncthreads();
#pragma unroll
    for (int ks = 0; ks < 64; ks += 16) {
      bf16x8 af[2], bfr[2];
#pragma unroll
      for (int at = 0; at < 2; at++) {
        int row = wm * 64 + at * 32 + l31;
        int pc = ((ks >> 3) + half) ^ (row & 7);
        af[at] = *(const bf16x8*)(As + row * 64 + pc * 8);
      }
#pragma unroll
      for (int nt = 0; nt < 2; nt++) {
        int row = wn * 64 + nt * 32 + l31;
        int pc = ((ks >> 3) + half) ^ (row & 7);
        bfr[nt] = *(const bf16x8*)(Bs + row * 64 + pc * 8);
      }
#pragma unroll
      for (int at = 0; at < 2; at++)
#pragma unroll
        for (int nt = 0; nt < 2; nt++)
          acc[at][nt] = __builtin_amdgcn_mfma_f32_32x32x16_bf16(af[at], bfr[nt], acc[at][nt], 0, 0, 0);
    }
    __syncthreads();
  }

#pragma unroll
  for (int at = 0; at < 2; at++)
#pragma unroll
    for (int nt = 0; nt < 2; nt++) {
      int col = n0 + wn * 64 + nt * 32 + l31;
      float bv, sc;
      int which = 0, cl = col;
      if (MODE == 0) {
        which = col >> 10; cl = col & 1023;
        const float* bp = (which == 0) ? b0 : ((which == 1) ? b1 : b2);
        bv = bp[cl];
        sc = (which == 0) ? SCQ : 1.f;
      } else {
        bv = b0[col]; sc = 1.f;
      }
#pragma unroll
      for (int reg = 0; reg < 16; reg++) {
        int row = m0 + wm * 64 + at * 32 + (reg & 3) + 8 * (reg >> 2) + 4 * half;
        float v = (acc[at][nt][reg] + bv) * sc;
        if (MODE == 0) {
          int h = cl >> 6, d = cl & 63;
          int b = row >> 11, t = row & 2047;
          ((unsigned short*)out)[(size_t)which * 8388608 +
                                 ((size_t)((b * 16 + h) * 2048 + t)) * 64 + d] = f2bf(v);
        } else {
          ((float*)out)[(size_t)row * N + col] = v;
        }
      }
    }
}

// ---------------- V transpose: V[bh][t][d] -> Vt[bh][d][t] ----------------
__global__ __launch_bounds__(256) void transpose_v(const unsigned short* __restrict__ V,
                                                   unsigned short* __restrict__ Vt) {
  constexpr int P = 66;
  __shared__ unsigned short L[64 * P];
  const int tid = threadIdx.x;
  const int bh = blockIdx.y;
  const int t0 = blockIdx.x * 64;
  const unsigned short* Vp = V + (size_t)bh * 2048 * 64;
  unsigned short* Op = Vt + (size_t)bh * 64 * 2048;
#pragma unroll
  for (int j = 0; j < 2; j++) {
    int r = (tid >> 3) + j * 32;
    int c = (tid & 7) * 8;
    u16x8 v = *(const u16x8*)(Vp + (size_t)(t0 + r) * 64 + c);
#pragma unroll
    for (int i = 0; i < 4; i++) {
      unsigned int pk = (unsigned int)v[2 * i] | ((unsigned int)v[2 * i + 1] << 16);
      *(unsigned int*)&L[r * P + c + 2 * i] = pk;
    }
  }
  __syncthreads();
#pragma unroll
  for (int j = 0; j < 2; j++) {
    int ch = j * 256 + tid;
    int d = ch >> 3, tc = (ch & 7) * 8;
    u16x8 o;
#pragma unroll
    for (int k = 0; k < 8; k++) o[k] = L[(tc + k) * P + d];
    *(u16x8*)(Op + (size_t)d * 2048 + t0 + tc) = o;
  }
}

// ---------------- attention inner tile: one 16-row q-tile vs one 64-col s-tile ----
#define PPITCH 72
__device__ __attribute__((always_inline)) inline
void attn_tile(int qt, int s0, const bf16x8* aq, const unsigned short* Ks,
               const unsigned short* Vs, unsigned short* pl,
               f32x4* o, float* lrow, int quad, int l15) {
  const bool full = (s0 + 63) <= qt;
  const int nsc = full ? 4 : (((qt + 15 - s0) >> 4) + 1);  // 1..4
  const int nsc2 = (nsc + 1) & ~1;

#pragma unroll
  for (int sc = 0; sc < 4; sc++) {
    if (sc < nsc) {
      f32x4 s = {};
#pragma unroll
      for (int kh = 0; kh < 2; kh++) {
        int kr = sc * 16 + l15;
        int pc = (kh * 4 + quad) ^ (kr & 7);
        u16x8 bku = *(const u16x8*)(Ks + kr * 64 + pc * 8);
        s = __builtin_amdgcn_mfma_f32_16x16x32_bf16(aq[kh], __builtin_bit_cast(bf16x8, bku), s, 0, 0, 0);
      }
      if (full) {
#pragma unroll
        for (int r = 0; r < 4; r++) {
          float e = fexp2(s[r]);
          lrow[r] += e;
          pl[(quad * 4 + r) * PPITCH + sc * 16 + l15] = f2bf_fast(e);
        }
      } else {
        int sg = s0 + sc * 16 + l15;
#pragma unroll
        for (int r = 0; r < 4; r++) {
          float e = fexp2(s[r]);
          e = (sg > qt + quad * 4 + r) ? 0.f : e;
          lrow[r] += e;
          pl[(quad * 4 + r) * PPITCH + sc * 16 + l15] = f2bf_fast(e);
        }
      }
    } else if (sc < nsc2) {
#pragma unroll
      for (int r = 0; r < 4; r++)
        pl[(quad * 4 + r) * PPITCH + sc * 16 + l15] = 0;
    }
  }
  __asm__ __volatile__("" ::: "memory");
#pragma unroll
  for (int h2 = 0; h2 < 2; h2++) {
    if (h2 * 2 < nsc2) {
      u16x8 apu = *(const u16x8*)(pl + l15 * PPITCH + h2 * 32 + quad * 8);
      bf16x8 ap = __builtin_bit_cast(bf16x8, apu);
#pragma unroll
      for (int dc = 0; dc < 4; dc++) {
        int vr = dc * 16 + l15;
        int pc = (h2 * 4 + quad) ^ (vr & 7);
        u16x8 vu = *(const u16x8*)(Vs + vr * 64 + pc * 8);
        o[dc] = __builtin_amdgcn_mfma_f32_16x16x32_bf16(ap, __builtin_bit_cast(bf16x8, vu), o[dc], 0, 0, 0);
      }
    }
  }
}

// ---------------- Flash attention (causal), dbuf LDS K/V, 2 q-tiles/wave ----------------
// Q (pre-scaled by 0.125*log2e),K: [B*H,T,D] bf16; Vt: [B*H,D,T]; Y: [B,T,H*D].
// Block p phase0: q-tiles {8p..8p+7} (wave w: 8p+w, 8p+4+w); phase1: mirror
// {127-8p-7..127-8p}. Each staged K/V tile serves 8 q-tiles; per-block work
// uniform (34 iters). K/V staging double-buffered: prefetch overlaps compute,
// one barrier per iteration (barrier drains vmcnt -> prefetch complete).
__global__ __launch_bounds__(256, 2) void attn_kernel(const unsigned short* __restrict__ Q,
                                                      const unsigned short* __restrict__ Km,
                                                      const unsigned short* __restrict__ Vt,
                                                      unsigned short* __restrict__ Y) {
  constexpr int T = 2048, D = 64;
  __shared__ __align__(16) unsigned short Ks[2][64 * 64];
  __shared__ __align__(16) unsigned short Vs[2][64 * 64];
  __shared__ __align__(16) unsigned short P_lds[4][16 * PPITCH];
  const int tid = threadIdx.x;
  const int lane = tid & 63, w = tid >> 6;
  const int quad = lane >> 4, l15 = lane & 15;
  const int bh = blockIdx.y;
  const int b = bh >> 4, h = bh & 15;
  const int p = blockIdx.x;  // 0..7
  const unsigned short* Qp = Q + (size_t)bh * T * D;
  const unsigned short* Kp = Km + (size_t)bh * T * D;
  const unsigned short* Vp = Vt + (size_t)bh * D * T;
  unsigned short* pl = P_lds[w];

  // staging constants (each wave stages 2x64 chunks of K and of V)
  const int bch0 = (w * 2) * 64, bch1 = (w * 2 + 1) * 64;
  const int ch0 = bch0 + lane, ch1 = bch1 + lane;
  const int row0 = ch0 >> 3, c0 = (ch0 & 7) ^ (row0 & 7);
  const int row1 = ch1 >> 3, c1 = (ch1 & 7) ^ (row1 & 7);

  for (int phase = 0; phase < 2; ++phase) {
    int jlo, jhi;
    if (!phase) { jlo = 8 * p + w; jhi = jlo + 4; }
    else        { jhi = 127 - 8 * p - w; jlo = jhi - 4; }
    const int qlo = jlo * 16, qhi = jhi * 16;
    const int nit = phase ? (32 - 2 * p) : (2 * p + 2);

    bf16x8 aqlo[2], aqhi[2];
    aqlo[0] = *(const bf16x8*)(Qp + (size_t)(qlo + l15) * D + quad * 8);
    aqlo[1] = *(const bf16x8*)(Qp + (size_t)(qlo + l15) * D + 32 + quad * 8);
    aqhi[0] = *(const bf16x8*)(Qp + (size_t)(qhi + l15) * D + quad * 8);
    aqhi[1] = *(const bf16x8*)(Qp + (size_t)(qhi + l15) * D + 32 + quad * 8);

    f32x4 olo[4] = {}, ohi[4] = {};
    float llo[4] = {0.f, 0.f, 0.f, 0.f}, lhi[4] = {0.f, 0.f, 0.f, 0.f};

    // prologue: stage tile 0 into buffer 0
    gload_lds16(Kp + (size_t)row0 * 64 + c0 * 8, Ks[0] + (size_t)bch0 * 8);
    gload_lds16(Kp + (size_t)row1 * 64 + c1 * 8, Ks[0] + (size_t)bch1 * 8);
    gload_lds16(Vp + (size_t)row0 * T + c0 * 8, Vs[0] + (size_t)bch0 * 8);
    gload_lds16(Vp + (size_t)row1 * T + c1 * 8, Vs[0] + (size_t)bch1 * 8);
    __syncthreads();

    for (int it = 0; it < nit; ++it) {
      const int s0 = it * 64;
      const int cur = it & 1, nxt = cur ^ 1;
      if (it + 1 < nit) {  // prefetch next tile during compute
        const int sn = s0 + 64;
        gload_lds16(Kp + (size_t)(sn + row0) * 64 + c0 * 8, Ks[nxt] + (size_t)bch0 * 8);
        gload_lds16(Kp + (size_t)(sn + row1) * 64 + c1 * 8, Ks[nxt] + (size_t)bch1 * 8);
        gload_lds16(Vp + (size_t)row0 * T + sn + c0 * 8, Vs[nxt] + (size_t)bch0 * 8);
        gload_lds16(Vp + (size_t)row1 * T + sn + c1 * 8, Vs[nxt] + (size_t)bch1 * 8);
      }
      if (s0 <= qlo + 15)
        attn_tile(qlo, s0, aqlo, Ks[cur], Vs[cur], pl, olo, llo, quad, l15);
      attn_tile(qhi, s0, aqhi, Ks[cur], Vs[cur], pl, ohi, lhi, quad, l15);
      __syncthreads();  // all reads of [cur] done; prefetch into [nxt] drained
    }

#pragma unroll
    for (int r = 0; r < 4; r++) {
      float ilo = 1.f / rowsum16(llo[r]);
      float ihi = 1.f / rowsum16(lhi[r]);
      int glo = qlo + quad * 4 + r, ghi = qhi + quad * 4 + r;
#pragma unroll
      for (int dc = 0; dc < 4; dc++) {
        Y[((size_t)(b * T + glo)) * 1024 + h * 64 + dc * 16 + l15] = f2bf(olo[dc][r] * ilo);
        Y[((size_t)(b * T + ghi)) * 1024 + h * 64 + dc * 16 + l15] = f2bf(ohi[dc][r] * ihi);
      }
    }
  }
}

// ---------------- launch ----------------
extern "C" void kernel_launch(void* const* d_in, const int* in_sizes, int n_in,
                              void* d_out, int out_size, void* d_ws, size_t ws_size,
                              hipStream_t stream) {
  const float* x  = (const float*)d_in[0];
  const float* Wq = (const float*)d_in[1];
  const float* bq = (const float*)d_in[2];
  const float* Wk = (const float*)d_in[3];
  const float* bk = (const float*)d_in[4];
  const float* Wv = (const float*)d_in[5];
  const float* bv = (const float*)d_in[6];
  const float* Wp = (const float*)d_in[7];
  const float* bp = (const float*)d_in[8];

  char* ws = (char*)d_ws;
  unsigned short* xb  = (unsigned short*)(ws + 0);          // 16 MiB: x bf16; later Vt
  unsigned short* wqb = (unsigned short*)(ws + 16777216);   // Wq,Wk,Wv contiguous = 3072x1024
  unsigned short* wkb = (unsigned short*)(ws + 18874368);
  unsigned short* wvb = (unsigned short*)(ws + 20971520);
  unsigned short* wpb = (unsigned short*)(ws + 23068672);
  unsigned short* Qb  = (unsigned short*)(ws + 25165824);   // Q,K,V contiguous, 16 MiB each
  unsigned short* Kb  = (unsigned short*)(ws + 41943040);
  unsigned short* Vb  = (unsigned short*)(ws + 58720256);
  unsigned short* Vtb = xb;  // x dead after fused QKV GEMM
  unsigned short* Yb  = Vb;  // V dead after transpose

  cvt_x<<<8192, 256, 0, stream>>>(x, xb);
  cvt_w<<<dim3(1024, 4), 256, 0, stream>>>(Wq, Wk, Wv, Wp, wqb, wkb, wvb, wpb);

  gemm128<0><<<dim3(64, 24), 256, 0, stream>>>(xb, wqb, bq, bk, bv, Qb, 8192, 3072, 1024);

  transpose_v<<<dim3(32, 64), 256, 0, stream>>>(Vb, Vtb);
  attn_kernel<<<dim3(8, 64), 256, 0, stream>>>(Qb, Kb, Vtb, Yb);

  gemm128<1><<<dim3(64, 8), 256, 0, stream>>>(Yb, wpb, bp, bp, bp, d_out, 8192, 1024, 1024);
}

// Round 7
// 257.510 us; speedup vs baseline: 1.0926x; 1.0926x over previous
//
#include <hip/hip_runtime.h>

typedef float f32x4 __attribute__((ext_vector_type(4)));
typedef float f32x16 __attribute__((ext_vector_type(16)));
typedef __bf16 bf16x8 __attribute__((ext_vector_type(8)));
typedef unsigned short u16x8 __attribute__((ext_vector_type(8)));

#define SCQ 0.1803368801111183f  // 0.125 * log2(e): softmax in exp2 domain

__device__ inline unsigned short f2bf(float f) {
  unsigned int u = __builtin_bit_cast(unsigned int, f);
  u += 0x7FFFu + ((u >> 16) & 1u);
  return (unsigned short)(u >> 16);
}
// round-half-up bf16 for nonneg values (2 VALU)
__device__ inline unsigned short f2bf_fast(float f) {
  unsigned int u = __builtin_bit_cast(unsigned int, f);
  return (unsigned short)((u + 0x8000u) >> 16);
}

__device__ inline float fexp2(float x) {
#if __has_builtin(__builtin_amdgcn_exp2f)
  return __builtin_amdgcn_exp2f(x);
#else
  return exp2f(x);
#endif
}

// DPP rotate within 16-lane row (VALU pipe)
template <int N>
__device__ inline float rowror(float v) {
  return __builtin_bit_cast(float, __builtin_amdgcn_update_dpp(
      0, __builtin_bit_cast(int, v), 0x120 | N, 0xF, 0xF, true));
}
__device__ inline float rowsum16(float v) {
  v += rowror<8>(v); v += rowror<4>(v);
  v += rowror<2>(v); v += rowror<1>(v);
  return v;
}

__device__ inline void gload_lds16(const unsigned short* g, unsigned short* l) {
  __builtin_amdgcn_global_load_lds(
      (const __attribute__((address_space(1))) unsigned int*)g,
      (__attribute__((address_space(3))) unsigned int*)l, 16, 0, 0);
}

// ---------------- fp32 -> bf16 conversion ----------------
__global__ void cvt_x(const float* __restrict__ in, unsigned short* __restrict__ out) {
  int i = (blockIdx.x * 256 + threadIdx.x) * 4;
  float4 f = *(const float4*)(in + i);
  ushort4 o;
  o.x = f2bf(f.x); o.y = f2bf(f.y); o.z = f2bf(f.z); o.w = f2bf(f.w);
  *(ushort4*)(out + i) = o;
}

__global__ void cvt_w(const float* __restrict__ a, const float* __restrict__ b,
                      const float* __restrict__ c, const float* __restrict__ d,
                      unsigned short* __restrict__ oa, unsigned short* __restrict__ ob,
                      unsigned short* __restrict__ oc, unsigned short* __restrict__ od) {
  const float* src[4] = {a, b, c, d};
  unsigned short* dst[4] = {oa, ob, oc, od};
  int m = blockIdx.y;
  int i = (blockIdx.x * 256 + threadIdx.x) * 4;
  float4 f = *(const float4*)(src[m] + i);
  ushort4 o;
  o.x = f2bf(f.x); o.y = f2bf(f.y); o.z = f2bf(f.z); o.w = f2bf(f.w);
  *(ushort4*)(dst[m] + i) = o;
}

// ---------------- GEMM: out[m][n] = sum_k A[m][k]*Bt[n][k] + bias[n] ----------------
// 128x128 tile, BK=64, global_load_lds width16, XOR-swizzled chunks,
// 32x32x16 MFMA (2x2 per wave, 64x64 wave tile).
// MODE 0: fused QKV (N=3072): which=col>>10 selects bias b{0,1,2}, Q pre-scaled
//         by SCQ, bf16 scatter into out + which*8M, [B,H,T,D] layout.
// MODE 1: fp32 row-major MxN with bias b0.
template <int MODE>
__global__ __launch_bounds__(256) void gemm128(const unsigned short* __restrict__ A,
                                               const unsigned short* __restrict__ Bt,
                                               const float* __restrict__ b0,
                                               const float* __restrict__ b1,
                                               const float* __restrict__ b2,
                                               void* __restrict__ out,
                                               int M, int N, int K) {
  __shared__ __align__(16) unsigned short As[128 * 64];
  __shared__ __align__(16) unsigned short Bs[128 * 64];
  const int tid = threadIdx.x;
  const int lane = tid & 63, w = tid >> 6;
  const int l31 = lane & 31, half = lane >> 5;
  const int wm = w & 1, wn = w >> 1;
  const int m0 = blockIdx.x * 128, n0 = blockIdx.y * 128;

  f32x16 acc[2][2] = {};

  for (int kb = 0; kb < K; kb += 64) {
#pragma unroll
    for (int j = 0; j < 4; j++) {
      int ch = j * 256 + w * 64 + lane;
      int row = ch >> 3, pc = ch & 7;
      int c = pc ^ (row & 7);
      gload_lds16(A + (size_t)(m0 + row) * K + kb + c * 8, As + (size_t)(j * 256 + w * 64) * 8);
      gload_lds16(Bt + (size_t)(n0 + row) * K + kb + c * 8, Bs + (size_t)(j * 256 + w * 64) * 8);
    }
    __syncthreads();
#pragma unroll
    for (int ks = 0; ks < 64; ks += 16) {
      bf16x8 af[2], bfr[2];
#pragma unroll
      for (int at = 0; at < 2; at++) {
        int row = wm * 64 + at * 32 + l31;
        int pc = ((ks >> 3) + half) ^ (row & 7);
        af[at] = *(const bf16x8*)(As + row * 64 + pc * 8);
      }
#pragma unroll
      for (int nt = 0; nt < 2; nt++) {
        int row = wn * 64 + nt * 32 + l31;
        int pc = ((ks >> 3) + half) ^ (row & 7);
        bfr[nt] = *(const bf16x8*)(Bs + row * 64 + pc * 8);
      }
#pragma unroll
      for (int at = 0; at < 2; at++)
#pragma unroll
        for (int nt = 0; nt < 2; nt++)
          acc[at][nt] = __builtin_amdgcn_mfma_f32_32x32x16_bf16(af[at], bfr[nt], acc[at][nt], 0, 0, 0);
    }
    __syncthreads();
  }

#pragma unroll
  for (int at = 0; at < 2; at++)
#pragma unroll
    for (int nt = 0; nt < 2; nt++) {
      int col = n0 + wn * 64 + nt * 32 + l31;
      float bv, sc;
      int which = 0, cl = col;
      if (MODE == 0) {
        which = col >> 10; cl = col & 1023;
        const float* bp = (which == 0) ? b0 : ((which == 1) ? b1 : b2);
        bv = bp[cl];
        sc = (which == 0) ? SCQ : 1.f;
      } else {
        bv = b0[col]; sc = 1.f;
      }
#pragma unroll
      for (int reg = 0; reg < 16; reg++) {
        int row = m0 + wm * 64 + at * 32 + (reg & 3) + 8 * (reg >> 2) + 4 * half;
        float v = (acc[at][nt][reg] + bv) * sc;
        if (MODE == 0) {
          int h = cl >> 6, d = cl & 63;
          int b = row >> 11, t = row & 2047;
          ((unsigned short*)out)[(size_t)which * 8388608 +
                                 ((size_t)((b * 16 + h) * 2048 + t)) * 64 + d] = f2bf(v);
        } else {
          ((float*)out)[(size_t)row * N + col] = v;
        }
      }
    }
}

// ---------------- V transpose: V[bh][t][d] -> Vt[bh][d][t] ----------------
__global__ __launch_bounds__(256) void transpose_v(const unsigned short* __restrict__ V,
                                                   unsigned short* __restrict__ Vt) {
  constexpr int P = 66;
  __shared__ unsigned short L[64 * P];
  const int tid = threadIdx.x;
  const int bh = blockIdx.y;
  const int t0 = blockIdx.x * 64;
  const unsigned short* Vp = V + (size_t)bh * 2048 * 64;
  unsigned short* Op = Vt + (size_t)bh * 64 * 2048;
#pragma unroll
  for (int j = 0; j < 2; j++) {
    int r = (tid >> 3) + j * 32;
    int c = (tid & 7) * 8;
    u16x8 v = *(const u16x8*)(Vp + (size_t)(t0 + r) * 64 + c);
#pragma unroll
    for (int i = 0; i < 4; i++) {
      unsigned int pk = (unsigned int)v[2 * i] | ((unsigned int)v[2 * i + 1] << 16);
      *(unsigned int*)&L[r * P + c + 2 * i] = pk;
    }
  }
  __syncthreads();
#pragma unroll
  for (int j = 0; j < 2; j++) {
    int ch = j * 256 + tid;
    int d = ch >> 3, tc = (ch & 7) * 8;
    u16x8 o;
#pragma unroll
    for (int k = 0; k < 8; k++) o[k] = L[(tc + k) * P + d];
    *(u16x8*)(Op + (size_t)d * 2048 + t0 + tc) = o;
  }
}

// ---------------- attention inner tile: one 16-row q-tile vs one 64-col s-tile ----
#define PPITCH 72
__device__ __attribute__((always_inline)) inline
void attn_tile(int qt, int s0, const bf16x8* aq, const unsigned short* Ks,
               const unsigned short* Vs, unsigned short* pl,
               f32x4* o, float* lrow, int quad, int l15) {
  const bool full = (s0 + 63) <= qt;
  const int nsc = full ? 4 : (((qt + 15 - s0) >> 4) + 1);  // 1..4
  const int nsc2 = (nsc + 1) & ~1;

#pragma unroll
  for (int sc = 0; sc < 4; sc++) {
    if (sc < nsc) {
      f32x4 s = {};
#pragma unroll
      for (int kh = 0; kh < 2; kh++) {
        int kr = sc * 16 + l15;
        int pc = (kh * 4 + quad) ^ (kr & 7);
        u16x8 bku = *(const u16x8*)(Ks + kr * 64 + pc * 8);
        s = __builtin_amdgcn_mfma_f32_16x16x32_bf16(aq[kh], __builtin_bit_cast(bf16x8, bku), s, 0, 0, 0);
      }
      if (full) {
#pragma unroll
        for (int r = 0; r < 4; r++) {
          float e = fexp2(s[r]);
          lrow[r] += e;
          pl[(quad * 4 + r) * PPITCH + sc * 16 + l15] = f2bf_fast(e);
        }
      } else {
        int sg = s0 + sc * 16 + l15;
#pragma unroll
        for (int r = 0; r < 4; r++) {
          float e = fexp2(s[r]);
          e = (sg > qt + quad * 4 + r) ? 0.f : e;
          lrow[r] += e;
          pl[(quad * 4 + r) * PPITCH + sc * 16 + l15] = f2bf_fast(e);
        }
      }
    } else if (sc < nsc2) {
#pragma unroll
      for (int r = 0; r < 4; r++)
        pl[(quad * 4 + r) * PPITCH + sc * 16 + l15] = 0;
    }
  }
  __asm__ __volatile__("" ::: "memory");
#pragma unroll
  for (int h2 = 0; h2 < 2; h2++) {
    if (h2 * 2 < nsc2) {
      u16x8 apu = *(const u16x8*)(pl + l15 * PPITCH + h2 * 32 + quad * 8);
      bf16x8 ap = __builtin_bit_cast(bf16x8, apu);
#pragma unroll
      for (int dc = 0; dc < 4; dc++) {
        int vr = dc * 16 + l15;
        int pc = (h2 * 4 + quad) ^ (vr & 7);
        u16x8 vu = *(const u16x8*)(Vs + vr * 64 + pc * 8);
        o[dc] = __builtin_amdgcn_mfma_f32_16x16x32_bf16(ap, __builtin_bit_cast(bf16x8, vu), o[dc], 0, 0, 0);
      }
    }
  }
}

// ---------------- Flash attention (causal), LDS-staged K/V, XCD-local bh ----------------
// Q (pre-scaled by 0.125*log2e),K: [B*H,T,D] bf16; Vt: [B*H,D,T]; Y: [B,T,H*D].
// Grid (64,16): bx=bh, by=p. Linear block id = p*64+bh -> XCD = bh%8 (round-
// robin dispatch), so all 16 p-blocks of one bh co-reside on one XCD and its
// K/V streams through that XCD's L2 (512 KB/bh vs 4 MiB L2).
// Block p phase0: waves handle q-tiles {4p..4p+3}; phase1: {127-4p-3..127-4p}.
// Every block exactly 33 iterations; every wave active in every iteration.
__global__ __launch_bounds__(256, 4) void attn_kernel(const unsigned short* __restrict__ Q,
                                                      const unsigned short* __restrict__ Km,
                                                      const unsigned short* __restrict__ Vt,
                                                      unsigned short* __restrict__ Y) {
  constexpr int T = 2048, D = 64;
  __shared__ __align__(16) unsigned short Ks[64 * 64];
  __shared__ __align__(16) unsigned short Vs[64 * 64];
  __shared__ __align__(16) unsigned short P_lds[4][16 * PPITCH];
  const int tid = threadIdx.x;
  const int lane = tid & 63, w = tid >> 6;
  const int quad = lane >> 4, l15 = lane & 15;
  const int bh = blockIdx.x;  // XCD = bh % 8
  const int b = bh >> 4, h = bh & 15;
  const int p = blockIdx.y;   // 0..15
  const unsigned short* Qp = Q + (size_t)bh * T * D;
  const unsigned short* Kp = Km + (size_t)bh * T * D;
  const unsigned short* Vp = Vt + (size_t)bh * D * T;
  unsigned short* pl = P_lds[w];

  // staging constants for this thread (same every iteration)
  const int bch0 = (w * 2) * 64, bch1 = (w * 2 + 1) * 64;
  const int ch0 = bch0 + lane, ch1 = bch1 + lane;
  const int row0 = ch0 >> 3, c0 = (ch0 & 7) ^ (row0 & 7);
  const int row1 = ch1 >> 3, c1 = (ch1 & 7) ^ (row1 & 7);

  for (int phase = 0; phase < 2; ++phase) {
    const int jt = phase ? (127 - (p * 4 + w)) : (p * 4 + w);
    const int qt = jt * 16;
    const int nit = phase ? (32 - p) : (p + 1);  // block-uniform iteration count

    bf16x8 aq[2];
    aq[0] = *(const bf16x8*)(Qp + (size_t)(qt + l15) * D + quad * 8);
    aq[1] = *(const bf16x8*)(Qp + (size_t)(qt + l15) * D + 32 + quad * 8);

    f32x4 o[4] = {};
    float lrow[4] = {0.f, 0.f, 0.f, 0.f};

    for (int it = 0; it < nit; ++it) {
      const int s0 = it * 64;
      // ---- stage K[s0..s0+63][0..63] and Vt[0..63][s0..s0+63] (4 instrs/wave) ----
      gload_lds16(Kp + (size_t)(s0 + row0) * 64 + c0 * 8, Ks + (size_t)bch0 * 8);
      gload_lds16(Kp + (size_t)(s0 + row1) * 64 + c1 * 8, Ks + (size_t)bch1 * 8);
      gload_lds16(Vp + (size_t)row0 * T + s0 + c0 * 8, Vs + (size_t)bch0 * 8);
      gload_lds16(Vp + (size_t)row1 * T + s0 + c1 * 8, Vs + (size_t)bch1 * 8);
      __syncthreads();

      attn_tile(qt, s0, aq, Ks, Vs, pl, o, lrow, quad, l15);

      __syncthreads();  // protect Ks/Vs before next iteration's staging
    }

#pragma unroll
    for (int r = 0; r < 4; r++) {
      float inv = 1.f / rowsum16(lrow[r]);
      int qg = qt + quad * 4 + r;
#pragma unroll
      for (int dc = 0; dc < 4; dc++)
        Y[((size_t)(b * T + qg)) * 1024 + h * 64 + dc * 16 + l15] = f2bf(o[dc][r] * inv);
    }
  }
}

// ---------------- launch ----------------
extern "C" void kernel_launch(void* const* d_in, const int* in_sizes, int n_in,
                              void* d_out, int out_size, void* d_ws, size_t ws_size,
                              hipStream_t stream) {
  const float* x  = (const float*)d_in[0];
  const float* Wq = (const float*)d_in[1];
  const float* bq = (const float*)d_in[2];
  const float* Wk = (const float*)d_in[3];
  const float* bk = (const float*)d_in[4];
  const float* Wv = (const float*)d_in[5];
  const float* bv = (const float*)d_in[6];
  const float* Wp = (const float*)d_in[7];
  const float* bp = (const float*)d_in[8];

  char* ws = (char*)d_ws;
  unsigned short* xb  = (unsigned short*)(ws + 0);          // 16 MiB: x bf16; later Vt
  unsigned short* wqb = (unsigned short*)(ws + 16777216);   // Wq,Wk,Wv contiguous = 3072x1024
  unsigned short* wkb = (unsigned short*)(ws + 18874368);
  unsigned short* wvb = (unsigned short*)(ws + 20971520);
  unsigned short* wpb = (unsigned short*)(ws + 23068672);
  unsigned short* Qb  = (unsigned short*)(ws + 25165824);   // Q,K,V contiguous, 16 MiB each
  unsigned short* Kb  = (unsigned short*)(ws + 41943040);
  unsigned short* Vb  = (unsigned short*)(ws + 58720256);
  unsigned short* Vtb = xb;  // x dead after fused QKV GEMM
  unsigned short* Yb  = Vb;  // V dead after transpose

  cvt_x<<<8192, 256, 0, stream>>>(x, xb);
  cvt_w<<<dim3(1024, 4), 256, 0, stream>>>(Wq, Wk, Wv, Wp, wqb, wkb, wvb, wpb);

  gemm128<0><<<dim3(64, 24), 256, 0, stream>>>(xb, wqb, bq, bk, bv, Qb, 8192, 3072, 1024);

  transpose_v<<<dim3(32, 64), 256, 0, stream>>>(Vb, Vtb);
  attn_kernel<<<dim3(64, 16), 256, 0, stream>>>(Qb, Kb, Vtb, Yb);

  gemm128<1><<<dim3(64, 8), 256, 0, stream>>>(Yb, wpb, bp, bp, bp, d_out, 8192, 1024, 1024);
}